// Round 10
// baseline (122.506 us; speedup 1.0000x reference)
//
#include <hip/hip_runtime.h>

#define NN 8192
#define DD 128
// ALPHA * log2(e)
#define C2 72.13475204444817f
#define LN2 0.6931471805599453f
#define NTILE 64   // 8192 / 128 row/col tiles
#define NTRI 2080  // NTILE*(NTILE+1)/2 upper-triangle tiles
#define NBLK 512   // tile_kernel grid: 2 blocks/CU, tail-free chunks

typedef __attribute__((ext_vector_type(8))) __bf16 bf16x8;
typedef __attribute__((ext_vector_type(4))) float f32x4;

#if __has_builtin(__builtin_amdgcn_exp2f)
#define EXP2F(x) __builtin_amdgcn_exp2f(x)
#else
#define EXP2F(x) exp2f(x)
#endif
#if __has_builtin(__builtin_amdgcn_sqrtf)
#define SQRTF(x) __builtin_amdgcn_sqrtf(x)
#else
#define SQRTF(x) sqrtf(x)
#endif
#if __has_builtin(__builtin_amdgcn_logf)
#define LOG2F(x) __builtin_amdgcn_logf(x)
#else
#define LOG2F(x) log2f(x)
#endif

__device__ __forceinline__ unsigned short f2bf(float f) {
  unsigned u = __float_as_uint(f);
  u += 0x7FFFu + ((u >> 16) & 1u);  // RNE
  return (unsigned short)(u >> 16);
}

// async global->LDS, 16B per lane, LDS dest = wave-uniform base + lane*16
__device__ __forceinline__ void gload_lds16(const void* g, void* l) {
  __builtin_amdgcn_global_load_lds(
      (const __attribute__((address_space(1))) void*)g,
      (__attribute__((address_space(3))) void*)l, 16, 0, 0);
}

// ---- DPP rotate-reduction: sum over each 16-lane DPP row, result in ALL
// lanes. v_add + row_ror:{1,2,4,8} -- pure VALU, no LDS-unit traffic.
__device__ __forceinline__ float dpp_row_sum16(float v) {
  v += __int_as_float(__builtin_amdgcn_update_dpp(
      0, __float_as_int(v), 0x121, 0xf, 0xf, true));  // row_ror:1
  v += __int_as_float(__builtin_amdgcn_update_dpp(
      0, __float_as_int(v), 0x122, 0xf, 0xf, true));  // row_ror:2
  v += __int_as_float(__builtin_amdgcn_update_dpp(
      0, __float_as_int(v), 0x124, 0xf, 0xf, true));  // row_ror:4
  v += __int_as_float(__builtin_amdgcn_update_dpp(
      0, __float_as_int(v), 0x128, 0xf, 0xf, true));  // row_ror:8
  return v;
}
// full 64-lane sum: DPP within rows, shuffles across rows
__device__ __forceinline__ float wave_sum64(float v) {
  v = dpp_row_sum16(v);
  v += __shfl_xor(v, 16, 64);
  v += __shfl_xor(v, 32, 64);
  return v;
}

// ------- kernel A: fused bf16-convert + exact fp32 positives ---------------
// block = 512 threads = 8 waves = one class (targets are arange(N)//8).
// xbf is stored XOR-SWIZZLED: element e of row i lands at 16B-chunk
// (e/8)^(i&7) within the 256B row. Block 0 zeroes the tiny scalars.
__global__ __launch_bounds__(512) void prep_pos_kernel(
    const float* __restrict__ x, unsigned short* __restrict__ xbf,
    float* __restrict__ pos_e, float* __restrict__ pos_d,
    float* __restrict__ accs, unsigned* __restrict__ cnt) {
  int w = threadIdx.x >> 6;    // wave = row within class; i&7 == w
  int lane = threadIdx.x & 63;
  int i = blockIdx.x * 8 + w;

  __shared__ float xs[8][128];
  __shared__ float sqs[8];

  const float* xr = x + (size_t)i * DD;
  float a = xr[lane], b = xr[lane + 64];
  xs[w][lane] = a;
  xs[w][lane + 64] = b;

  float s = wave_sum64(__fmaf_rn(a, a, b * b));
  if (lane == 0) sqs[w] = s;
  // swizzled bf16 store: chunk t of 8 elements -> chunk t ^ w
  unsigned short* o = xbf + (size_t)i * DD;
  int t1 = lane >> 3, e1 = lane & 7;
  o[((t1 ^ w) << 3) + e1] = f2bf(a);        // elements 0..63 (chunks 0..7)
  o[64 + ((t1 ^ w) << 3) + e1] = f2bf(b);   // elements 64..127 (chunks 8..15)
  if (blockIdx.x == 0) {
    if (threadIdx.x == 0) {
      accs[0] = 0.f;
      accs[1] = 0.f;
      accs[2] = 0.f;
    }
    if (threadIdx.x == 1) cnt[0] = 0u;
  }

  __syncthreads();
  float sqi = sqs[w];
  float pe = 0.f, pd = 0.f;
  for (int j = 0; j < 8; ++j) {
    if (j == w) continue;  // wave-uniform
    float dot =
        wave_sum64(__fmaf_rn(a, xs[j][lane], b * xs[j][lane + 64]));
    float d2 = fmaxf(__fmaf_rn(-2.f, dot, sqi + sqs[j]), 1e-12f);
    float dist = SQRTF(d2);
    pe += EXP2F(__fmaf_rn(dist, -C2, C2));
    pd += dist;
  }
  if (lane == 0) {
    pos_e[i] = pe;
    pos_d[i] = pd;
  }
}

// ---------------- kernel B: software-pipelined triangular MFMA v7 ----------
// R9 showed 2 blocks/CU bought only -2.3us: each barrier window still holds
// two serially-dependent phases per wave ([ds_read+MFMA] -> [epilogue]), so
// pipes alternate idle/saturated in lockstep. v7 carries the accumulator
// across iterations: iteration i computes MFMA(tile i)->accC while running
// epilogue(tile i-1) from accP -- zero data dependence, disjoint pipes,
// same scheduling region -> compiler interleaves. Barriers/tile unchanged;
// staging/parity scheme identical shifted by one; element math order
// unchanged (bit-identical outputs). Cost: accP+accC = 64 VGPR (live set
// ~125 <= 128 cap) + a 32-mov acc copy per tile.
__global__ __launch_bounds__(512, 4) void tile_kernel(
    const unsigned short* __restrict__ xbf, float* __restrict__ part,
    float* __restrict__ dpart) {
  int lane = threadIdx.x & 63;
  int wave = threadIdx.x >> 6;
  int q = lane >> 4, c = lane & 15;
  int rq = wave >> 1, ch = wave & 1;

  // chunk of the linear tile enumeration: [k0, k1)
  int k0 = (65 * blockIdx.x) >> 4, k1 = (65 * (blockIdx.x + 1)) >> 4;
  // decode k0 -> (tr, tc): P(tr) = tr*(129-tr)/2
  int tr = (int)((129.0f - SQRTF(16641.0f - 8.0f * (float)k0)) * 0.5f);
  while (tr > 0 && tr * (129 - tr) / 2 > k0) --tr;
  while ((tr + 1) * (128 - tr) / 2 <= k0) ++tr;
  int tc = tr + (k0 - tr * (129 - tr) / 2);

  __shared__ char panelB[65536];        // two 32KB B buffers
  __shared__ float rowsumW[2][2][128];  // [parity][ch][row]
  __shared__ float colsumW[2][4][128];  // [parity][rq][col]
  __shared__ float partd[8];

  int swz8 = (c & 7);  // ushort-chunk xor
  int goffB = wave * 4096 + lane * 16;

  bf16x8 ar[2][4];  // A fragments for this wave's 32-row strip
  int atr = tr;
  float dacc = 0.f;

  auto load_ar = [&](int I0a) {
#pragma unroll
    for (int rb = 0; rb < 2; ++rb) {
      const unsigned short* rp = xbf + (size_t)(I0a + rb * 16 + c) * DD;
#pragma unroll
      for (int ks = 0; ks < 4; ++ks)
        ar[rb][ks] = *(const bf16x8*)(rp + (((ks * 4 + q) ^ swz8) << 3));
    }
  };
  auto stage_panel = [&](int col, int buf) {
    const char* gB = (const char*)xbf + (size_t)col * 32768;
    char* lB = panelB + buf * 32768 + wave * 4096;
#pragma unroll
    for (int t = 0; t < 4; ++t)
      gload_lds16(gB + t * 1024 + goffB, lB + t * 1024);
  };
  auto do_mfma = [&](int buf, f32x4(&A)[2][4]) {
    const char* pb = panelB + buf * 32768 + ch * 16384 + c * 256;
#pragma unroll
    for (int ks = 0; ks < 4; ++ks) {
      int koff = (ks * 64 + q * 16) ^ (swz8 << 4);
      bf16x8 br[4];
#pragma unroll
      for (int cb = 0; cb < 4; ++cb)
        br[cb] = *(const bf16x8*)(pb + cb * 4096 + koff);
#pragma unroll
      for (int rb = 0; rb < 2; ++rb)
#pragma unroll
        for (int cb = 0; cb < 4; ++cb)
          A[rb][cb] = __builtin_amdgcn_mfma_f32_16x16x32_bf16(
              ar[rb][ks], br[cb], A[rb][cb], 0, 0, 0);
    }
  };
  // epilogue for a finished tile: C/D mapping col=lane&15, row=q*4+reg.
  // d2 = 2 - 2*dot (unit-norm rows); no fmax (self-pair NaN lanes get
  // overwritten by the cndmask constants in the diag branch).
  auto do_epilogue = [&](f32x4(&A)[2][4], int I0e, int J0e, bool diagE,
                         int par) {
    float tote[8];
#pragma unroll
    for (int kk = 0; kk < 8; ++kk) tote[kk] = 0.f;
    float pcol[4] = {0.f, 0.f, 0.f, 0.f};
    float totd = 0.f;
    if (!diagE) {  // 97% of tiles
#pragma unroll
      for (int rb = 0; rb < 2; ++rb) {
#pragma unroll
        for (int cb = 0; cb < 4; ++cb) {
#pragma unroll
          for (int r = 0; r < 4; ++r) {
            float d2 = __fmaf_rn(-2.f, A[rb][cb][r], 2.0f);
            float dist = SQRTF(d2);
            float ex = EXP2F(__fmaf_rn(dist, -C2, C2));
            tote[rb * 4 + r] += ex;
            pcol[cb] += ex;
            totd += dist;
          }
        }
      }
      dacc += 2.f * totd;  // off-diag counts twice (symmetry)
    } else {
#pragma unroll
      for (int rb = 0; rb < 2; ++rb) {
#pragma unroll
        for (int cb = 0; cb < 4; ++cb) {
          bool diagSub = (I0e + rb * 16) == (J0e + cb * 16);
#pragma unroll
          for (int r = 0; r < 4; ++r) {
            float d2 = __fmaf_rn(-2.f, A[rb][cb][r], 2.0f);
            float dist = SQRTF(d2);
            float ex = EXP2F(__fmaf_rn(dist, -C2, C2));
            if (diagSub && (q * 4 + r) == c) {  // exclude self-pair
              ex = 0.f;
              dist = 0.f;
            }
            tote[rb * 4 + r] += ex;
            totd += dist;
          }
        }
      }
      dacc += totd;
    }
    // row sums: DPP rotate-reduce across the 16 column-lanes (pure VALU)
#pragma unroll
    for (int kk = 0; kk < 8; ++kk) tote[kk] = dpp_row_sum16(tote[kk]);
    if (c == 0) {
#pragma unroll
      for (int rb = 0; rb < 2; ++rb)
#pragma unroll
        for (int r = 0; r < 4; ++r)
          rowsumW[par][ch][rq * 32 + rb * 16 + q * 4 + r] = tote[rb * 4 + r];
    }
    // column sums: reduce over the 4 q-groups (crosses DPP rows -> shfl)
    if (!diagE) {
#pragma unroll
      for (int cb = 0; cb < 4; ++cb) {
        float cs = pcol[cb];
        cs += __shfl_xor(cs, 16, 64);
        cs += __shfl_xor(cs, 32, 64);
        if (q == 0) colsumW[par][rq][ch * 64 + cb * 16 + c] = cs;
      }
    }
  };
  auto do_stores = [&](int trS, int tcS, bool diagS, int par) {
    size_t rslot = ((size_t)trS * NTILE + tcS) * 128;
    size_t cslot = ((size_t)tcS * NTILE + trS) * 128;
    int t = threadIdx.x;
    if (t < 128) {
      part[rslot + t] = rowsumW[par][0][t] + rowsumW[par][1][t];
    } else if (t < 256 && !diagS) {
      int t2 = t - 128;
      part[cslot + t2] = colsumW[par][0][t2] + colsumW[par][1][t2] +
                         colsumW[par][2][t2] + colsumW[par][3][t2];
    }
  };

  // ---- prologue: A preload + stage B(k0) ----
  load_ar(tr * 128 + rq * 32);
  stage_panel(tc, 0);
  __syncthreads();  // drain prologue staging + A preload

  // ---- prologue compute: MFMA for tile k0 -> accP ----
  f32x4 accP[2][4];
#pragma unroll
  for (int rb = 0; rb < 2; ++rb)
#pragma unroll
    for (int cb = 0; cb < 4; ++cb) accP[rb][cb] = (f32x4){0.f, 0.f, 0.f, 0.f};
  int trP = tr, tcP = tc;
  int I0P = tr * 128 + rq * 32, J0P = tc * 128 + ch * 64;
  bool diagP = (trP == tcP);
  if (tc + 1 < 64) {
    ++tc;
  } else {
    ++tr;
    tc = tr;
  }
  if (k0 + 1 < k1) stage_panel(tc, 1);  // B(k0+1)
  do_mfma(0, accP);
  __syncthreads();  // drains stage(k0+1); covered by MFMA(k0)

  // ---- main loop: iteration i = MFMA(tile i) + epilogue(tile i-1) ----
  for (int i = k0 + 1; i < k1; ++i) {
    int cur = (i - k0) & 1;       // buffer holding B(i); also sums parity
    int I0 = tr * 128 + rq * 32;  // tile i params
    if (atr != tr) {  // A-reload before stage -> counted vmcnt on consume
      atr = tr;
      load_ar(I0);
    }
    int J0 = tc * 128 + ch * 64;
    bool diag = (tr == tc);
    int trC = tr, tcC = tc;
    if (tc + 1 < 64) {
      ++tc;
    } else {
      ++tr;
      tc = tr;
    }
    if (i + 1 < k1) stage_panel(tc, cur ^ 1);  // B(i+1)

    f32x4 accC[2][4];
#pragma unroll
    for (int rb = 0; rb < 2; ++rb)
#pragma unroll
      for (int cb = 0; cb < 4; ++cb)
        accC[rb][cb] = (f32x4){0.f, 0.f, 0.f, 0.f};
    do_mfma(cur, accC);                       // LDS+MFMA pipes: tile i
    do_epilogue(accP, I0P, J0P, diagP, cur);  // VALU+trans pipes: tile i-1

    __syncthreads();  // sums visible; drains stage(i+1)
    do_stores(trP, tcP, diagP, cur);

    // roll pipeline state
#pragma unroll
    for (int rb = 0; rb < 2; ++rb)
#pragma unroll
      for (int cb = 0; cb < 4; ++cb) accP[rb][cb] = accC[rb][cb];
    trP = trC;
    tcP = tcC;
    I0P = I0;
    J0P = J0;
    diagP = diag;
  }

  // ---- tail: epilogue + stores for the last tile ----
  {
    int par = (k1 - k0) & 1;
    do_epilogue(accP, I0P, J0P, diagP, par);
    __syncthreads();
    do_stores(trP, tcP, diagP, par);
  }

  // block distance sum -> dpart[block] (plain store, no atomics)
  dacc = wave_sum64(dacc);
  if (lane == 0) partd[wave] = dacc;
  __syncthreads();
  if (threadIdx.x == 0) {
    float sacc = 0.f;
#pragma unroll
    for (int w2 = 0; w2 < 8; ++w2) sacc += partd[w2];
    dpart[blockIdx.x] = sacc;
  }
}

// ---------------- kernel C: reduce + final scalars -------------------------
// 64 blocks x 128 threads: block a reduces tot_e for rows a*128..+127 from
// part[a][t][c] (coalesced 512B rows), computes log terms inline, plus an
// 8-entry strip of dpart. Last-done block (fence + device atomic counter)
// finalizes the 4 outputs.
__global__ __launch_bounds__(128) void fin_kernel(
    const float* __restrict__ part, const float* __restrict__ dpart,
    const float* __restrict__ pos_e, const float* __restrict__ pos_d,
    float* accs, unsigned* cnt, float* __restrict__ out) {
  int a = blockIdx.x, c = threadIdx.x;
  const float* pa = part + (size_t)a * NTILE * 128 + c;
  float tot = 0.f;
#pragma unroll
  for (int t = 0; t < 64; ++t) tot += pa[(size_t)t * 128];
  int i = a * 128 + c;
  float p = pos_e[i];
  float denom = __fmaf_rn(0.5f, tot - p, p);  // p + 0.5*(tot - p)
  float lsum = LOG2F(denom) - LOG2F(p);       // -log(p/(p+neg)) / ln2
  float pdsum = pos_d[i];
  float ds = (c < 8) ? dpart[a * 8 + c] : 0.f;

  __shared__ float s1[128], s2[128], s3[128];
  s1[c] = lsum;
  s2[c] = pdsum;
  s3[c] = ds;
  __syncthreads();
  for (int w = 64; w; w >>= 1) {
    if (c < w) {
      s1[c] += s1[c + w];
      s2[c] += s2[c + w];
      s3[c] += s3[c + w];
    }
    __syncthreads();
  }
  if (c == 0) {
    atomicAdd(&accs[0], s1[0]);
    atomicAdd(&accs[1], s2[0]);
    atomicAdd(&accs[2], s3[0]);
    __threadfence();
    unsigned old = atomicAdd(cnt, 1u);
    if (old == 63u) {  // all 64 blocks' adds are visible
      float L = atomicAdd(&accs[0], 0.f);
      float PD = atomicAdd(&accs[1], 0.f);
      float DS = atomicAdd(&accs[2], 0.f);
      out[0] = L * LN2 / (float)NN;               // loss
      out[1] = 1.0f;                              // prec
      out[2] = PD / (float)(NN * 7);              // pos_d
      out[3] = (DS - PD) / ((float)NN * 8184.f);  // neg_d
    }
  }
}

extern "C" void kernel_launch(void* const* d_in, const int* in_sizes, int n_in,
                              void* d_out, int out_size, void* d_ws,
                              size_t ws_size, hipStream_t stream) {
  const float* x = (const float*)d_in[0];
  float* out = (float*)d_out;
  char* ws = (char*)d_ws;

  unsigned short* xbf = (unsigned short*)ws;          // 2 MB (swizzled layout)
  float* pos_e = (float*)(ws + (size_t)NN * DD * 2);  // 32 KB each
  float* pos_d = pos_e + NN;
  float* part = pos_d + NN;                           // 64*64*128 f32 = 2 MB
  float* dpart = part + (size_t)NTILE * NTILE * 128;  // NBLK floats
  float* accs = dpart + NBLK;                         // 3 floats
  unsigned* cnt = (unsigned*)(accs + 3);              // 1 u32

  prep_pos_kernel<<<NN / 8, 512, 0, stream>>>(x, xbf, pos_e, pos_d, accs, cnt);
  tile_kernel<<<NBLK, 512, 0, stream>>>(xbf, part, dpart);
  fin_kernel<<<64, 128, 0, stream>>>(part, dpart, pos_e, pos_d, accs, cnt,
                                     out);
}

// Round 11
// 112.005 us; speedup vs baseline: 1.0937x; 1.0937x over previous
//
#include <hip/hip_runtime.h>

#define NN 8192
#define DD 128
// ALPHA * log2(e)
#define C2 72.13475204444817f
#define LN2 0.6931471805599453f
#define NTILE 64   // 8192 / 128 row/col tiles
#define NTRI 2080  // NTILE*(NTILE+1)/2 upper-triangle tiles
#define NBLK 512   // tile_kernel grid: 2 blocks/CU, tail-free chunks

typedef __attribute__((ext_vector_type(8))) __bf16 bf16x8;
typedef __attribute__((ext_vector_type(4))) float f32x4;

#if __has_builtin(__builtin_amdgcn_exp2f)
#define EXP2F(x) __builtin_amdgcn_exp2f(x)
#else
#define EXP2F(x) exp2f(x)
#endif
#if __has_builtin(__builtin_amdgcn_sqrtf)
#define SQRTF(x) __builtin_amdgcn_sqrtf(x)
#else
#define SQRTF(x) sqrtf(x)
#endif
#if __has_builtin(__builtin_amdgcn_logf)
#define LOG2F(x) __builtin_amdgcn_logf(x)
#else
#define LOG2F(x) log2f(x)
#endif

__device__ __forceinline__ unsigned short f2bf(float f) {
  unsigned u = __float_as_uint(f);
  u += 0x7FFFu + ((u >> 16) & 1u);  // RNE
  return (unsigned short)(u >> 16);
}

// async global->LDS, 16B per lane, LDS dest = wave-uniform base + lane*16
__device__ __forceinline__ void gload_lds16(const void* g, void* l) {
  __builtin_amdgcn_global_load_lds(
      (const __attribute__((address_space(1))) void*)g,
      (__attribute__((address_space(3))) void*)l, 16, 0, 0);
}

// ---- DPP rotate-reduction: sum over each 16-lane DPP row, result in ALL
// lanes. v_add + row_ror:{1,2,4,8} -- pure VALU, no LDS-unit traffic.
__device__ __forceinline__ float dpp_row_sum16(float v) {
  v += __int_as_float(__builtin_amdgcn_update_dpp(
      0, __float_as_int(v), 0x121, 0xf, 0xf, true));  // row_ror:1
  v += __int_as_float(__builtin_amdgcn_update_dpp(
      0, __float_as_int(v), 0x122, 0xf, 0xf, true));  // row_ror:2
  v += __int_as_float(__builtin_amdgcn_update_dpp(
      0, __float_as_int(v), 0x124, 0xf, 0xf, true));  // row_ror:4
  v += __int_as_float(__builtin_amdgcn_update_dpp(
      0, __float_as_int(v), 0x128, 0xf, 0xf, true));  // row_ror:8
  return v;
}
// full 64-lane sum: DPP within rows, shuffles across rows
__device__ __forceinline__ float wave_sum64(float v) {
  v = dpp_row_sum16(v);
  v += __shfl_xor(v, 16, 64);
  v += __shfl_xor(v, 32, 64);
  return v;
}

// ------- kernel A: fused bf16-convert + exact fp32 positives ---------------
// block = 512 threads = 8 waves = one class (targets are arange(N)//8).
// xbf is stored XOR-SWIZZLED: element e of row i lands at 16B-chunk
// (e/8)^(i&7) within the 256B row. Block 0 zeroes the tiny scalars.
__global__ __launch_bounds__(512) void prep_pos_kernel(
    const float* __restrict__ x, unsigned short* __restrict__ xbf,
    float* __restrict__ pos_e, float* __restrict__ pos_d,
    float* __restrict__ accs, unsigned* __restrict__ cnt) {
  int w = threadIdx.x >> 6;    // wave = row within class; i&7 == w
  int lane = threadIdx.x & 63;
  int i = blockIdx.x * 8 + w;

  __shared__ float xs[8][128];
  __shared__ float sqs[8];

  const float* xr = x + (size_t)i * DD;
  float a = xr[lane], b = xr[lane + 64];
  xs[w][lane] = a;
  xs[w][lane + 64] = b;

  float s = wave_sum64(__fmaf_rn(a, a, b * b));
  if (lane == 0) sqs[w] = s;
  // swizzled bf16 store: chunk t of 8 elements -> chunk t ^ w
  unsigned short* o = xbf + (size_t)i * DD;
  int t1 = lane >> 3, e1 = lane & 7;
  o[((t1 ^ w) << 3) + e1] = f2bf(a);        // elements 0..63 (chunks 0..7)
  o[64 + ((t1 ^ w) << 3) + e1] = f2bf(b);   // elements 64..127 (chunks 8..15)
  if (blockIdx.x == 0) {
    if (threadIdx.x == 0) {
      accs[0] = 0.f;
      accs[1] = 0.f;
      accs[2] = 0.f;
    }
    if (threadIdx.x == 1) cnt[0] = 0u;
  }

  __syncthreads();
  float sqi = sqs[w];
  float pe = 0.f, pd = 0.f;
  for (int j = 0; j < 8; ++j) {
    if (j == w) continue;  // wave-uniform
    float dot =
        wave_sum64(__fmaf_rn(a, xs[j][lane], b * xs[j][lane + 64]));
    float d2 = fmaxf(__fmaf_rn(-2.f, dot, sqi + sqs[j]), 1e-12f);
    float dist = SQRTF(d2);
    pe += EXP2F(__fmaf_rn(dist, -C2, C2));
    pd += dist;
  }
  if (lane == 0) {
    pos_e[i] = pe;
    pos_d[i] = pd;
  }
}

// ---------------- kernel B: triangular MFMA kernel v8 ----------------------
// R10 post-mortem: acc double-buffering spilled (VGPR cap 128; FETCH/WRITE
// ballooned to 86/84 MB of scratch) -- reverted. v8 keeps the verified v6
// outer structure and attacks the LDS pipe, which the R7(-5.1us DPP) /
// R8(-1.6 VALU trim) / R9(-2.3 occupancy) pattern identifies as the
// saturated per-CU resource: with the old (32row x 64col) wave split, the
// 4 waves sharing a column-half read IDENTICAL B fragments (4x redundancy,
// 128 ds_read_b128/block/tile ~= 9.7us of LDS pipe per CU). v8 reshapes
// wave ownership to 64 rows x 32 cols (rh = wave>>2, cq = wave&3):
// B-reads halve to 64/block/tile; A registers double to ar[4][4] (64 VGPR,
// live set ~125 <= 128 -- falsifier: FETCH/WRITE balloon = spill, revert).
// MFMA count, staging, swizzle, parity, store scheme unchanged.
__global__ __launch_bounds__(512, 4) void tile_kernel(
    const unsigned short* __restrict__ xbf, float* __restrict__ part,
    float* __restrict__ dpart) {
  int lane = threadIdx.x & 63;
  int wave = threadIdx.x >> 6;
  int q = lane >> 4, c = lane & 15;
  int rh = wave >> 2, cq = wave & 3;  // 64-row half, 32-col quarter

  // chunk of the linear tile enumeration: [k0, k1)
  int k0 = (65 * blockIdx.x) >> 4, k1 = (65 * (blockIdx.x + 1)) >> 4;
  // decode k0 -> (tr, tc): P(tr) = tr*(129-tr)/2
  int tr = (int)((129.0f - SQRTF(16641.0f - 8.0f * (float)k0)) * 0.5f);
  while (tr > 0 && tr * (129 - tr) / 2 > k0) --tr;
  while ((tr + 1) * (128 - tr) / 2 <= k0) ++tr;
  int tc = tr + (k0 - tr * (129 - tr) / 2);

  __shared__ char panelB[65536];        // two 32KB B buffers
  __shared__ float rowsumW[2][4][128];  // [parity][cq][row]
  __shared__ float colsumW[2][2][128];  // [parity][rh][col]
  __shared__ float partd[8];

  int swz8 = (c & 7);  // ushort-chunk xor
  int goffB = wave * 4096 + lane * 16;

  bf16x8 ar[4][4];  // A fragments for this wave's 64-row strip
  int atr = tr;
  float dacc = 0.f;

  // prologue A-preload for tr0 (covered by the prologue barrier drain)
  {
    int I0p = tr * 128 + rh * 64;
#pragma unroll
    for (int rb = 0; rb < 4; ++rb) {
      const unsigned short* rp = xbf + (size_t)(I0p + rb * 16 + c) * DD;
#pragma unroll
      for (int ks = 0; ks < 4; ++ks)
        ar[rb][ks] = *(const bf16x8*)(rp + (((ks * 4 + q) ^ swz8) << 3));
    }
  }

  // prologue: stage B(k0); each wave stages a contiguous 4KB slice
  {
    const char* gB = (const char*)xbf + (size_t)tc * 32768;
    char* lB = panelB + wave * 4096;
#pragma unroll
    for (int t = 0; t < 4; ++t) gload_lds16(gB + t * 1024 + goffB, lB + t * 1024);
  }

  __syncthreads();  // drain prologue staging (+ A preload)

  for (int k = k0; k < k1; ++k) {
    int cur = (k - k0) & 1;
    int I0 = tr * 128 + rh * 64;  // wave row base (global)
    int J0 = tc * 128 + cq * 32;  // wave col base (global)
    bool diag = (tr == tc);

    // A-reload on row change, ISSUED BEFORE the B-prefetch so its consumer
    // waits a counted vmcnt (B loads may stay in flight).
    if (atr != tr) {
      atr = tr;
#pragma unroll
      for (int rb = 0; rb < 4; ++rb) {
        const unsigned short* rp = xbf + (size_t)(I0 + rb * 16 + c) * DD;
#pragma unroll
        for (int ks = 0; ks < 4; ++ks)
          ar[rb][ks] = *(const bf16x8*)(rp + (((ks * 4 + q) ^ swz8) << 3));
      }
    }

    // prefetch next B panel (next tile is (tr,tc+1) or (tr+1,tr+1))
    if (k + 1 < k1) {
      int tcn = (tc + 1 < 64) ? tc + 1 : tr + 1;
      const char* gB = (const char*)xbf + (size_t)tcn * 32768;
      char* lB = panelB + (cur ^ 1) * 32768 + wave * 4096;
#pragma unroll
      for (int t = 0; t < 4; ++t)
        gload_lds16(gB + t * 1024 + goffB, lB + t * 1024);
    }

    f32x4 acc[4][2];
#pragma unroll
    for (int rb = 0; rb < 4; ++rb)
#pragma unroll
      for (int cb = 0; cb < 2; ++cb)
        acc[rb][cb] = (f32x4){0.f, 0.f, 0.f, 0.f};

    // B fragments from LDS: 8 ds_read_b128/wave/tile (was 16 -- the 4x
    // read redundancy of the old split is now 2x)
    {
      const char* pb = panelB + cur * 32768 + cq * 8192 + c * 256;
#pragma unroll
      for (int ks = 0; ks < 4; ++ks) {
        int koff = (ks * 64 + q * 16) ^ (swz8 << 4);
        bf16x8 br[2];
#pragma unroll
        for (int cb = 0; cb < 2; ++cb)
          br[cb] = *(const bf16x8*)(pb + cb * 4096 + koff);
#pragma unroll
        for (int rb = 0; rb < 4; ++rb)
#pragma unroll
          for (int cb = 0; cb < 2; ++cb)
            acc[rb][cb] = __builtin_amdgcn_mfma_f32_16x16x32_bf16(
                ar[rb][ks], br[cb], acc[rb][cb], 0, 0, 0);
      }
    }

    // epilogue: C/D mapping col = lane&15, row = q*4 + reg (m89-verified)
    // d2 = 2 - 2*dot (unit-norm rows). No fmax: only self-pairs can give
    // d2<0 -> NaN, and those lanes are overwritten by the cndmask below.
    float tote[16];
#pragma unroll
    for (int kk = 0; kk < 16; ++kk) tote[kk] = 0.f;
    float pcol[2] = {0.f, 0.f};
    float totd = 0.f;

    if (!diag) {  // 97% of tiles: no self-pair logic at all
#pragma unroll
      for (int rb = 0; rb < 4; ++rb) {
#pragma unroll
        for (int cb = 0; cb < 2; ++cb) {
#pragma unroll
          for (int r = 0; r < 4; ++r) {
            float d2 = __fmaf_rn(-2.f, acc[rb][cb][r], 2.0f);
            float dist = SQRTF(d2);
            float ex = EXP2F(__fmaf_rn(dist, -C2, C2));
            tote[rb * 4 + r] += ex;
            pcol[cb] += ex;
            totd += dist;
          }
        }
      }
      dacc += 2.f * totd;  // off-diag counts twice (symmetry)
    } else {  // diag tile: self-pair zeroing; pcol not needed (never stored)
#pragma unroll
      for (int rb = 0; rb < 4; ++rb) {
#pragma unroll
        for (int cb = 0; cb < 2; ++cb) {
          bool diagSub = (rh * 4 + rb) == (cq * 2 + cb);  // same 16-block
#pragma unroll
          for (int r = 0; r < 4; ++r) {
            float d2 = __fmaf_rn(-2.f, acc[rb][cb][r], 2.0f);
            float dist = SQRTF(d2);
            float ex = EXP2F(__fmaf_rn(dist, -C2, C2));
            if (diagSub && (q * 4 + r) == c) {  // exclude self-pair
              ex = 0.f;
              dist = 0.f;
            }
            tote[rb * 4 + r] += ex;
            totd += dist;
          }
        }
      }
      dacc += totd;
    }

    // row sums: DPP rotate-reduce across the 16 column-lanes (pure VALU).
    // q-group g holds row rb*16 + g*4 + r after the reduce.
#pragma unroll
    for (int kk = 0; kk < 16; ++kk) tote[kk] = dpp_row_sum16(tote[kk]);
    if (c == 0) {
#pragma unroll
      for (int rb = 0; rb < 4; ++rb)
#pragma unroll
        for (int r = 0; r < 4; ++r)
          rowsumW[cur][cq][rh * 64 + rb * 16 + q * 4 + r] = tote[rb * 4 + r];
    }
    // column sums: reduce over the 4 q-groups (crosses DPP rows -> shfl)
    if (!diag) {
#pragma unroll
      for (int cb = 0; cb < 2; ++cb) {
        float cs = pcol[cb];
        cs += __shfl_xor(cs, 16, 64);
        cs += __shfl_xor(cs, 32, 64);
        if (q == 0) colsumW[cur][rh][cq * 32 + cb * 16 + c] = cs;
      }
    }

    __syncthreads();  // sums visible; drains vmcnt (B(k+1) covered by tile)

    // slot stores (each upper-triangle slot written exactly once, grid-wide)
    size_t rslot = ((size_t)tr * NTILE + tc) * 128;
    size_t cslot = ((size_t)tc * NTILE + tr) * 128;
    int t = threadIdx.x;
    if (t < 128) {
      part[rslot + t] = rowsumW[cur][0][t] + rowsumW[cur][1][t] +
                        rowsumW[cur][2][t] + rowsumW[cur][3][t];
    } else if (t < 256 && !diag) {
      int t2 = t - 128;
      part[cslot + t2] = colsumW[cur][0][t2] + colsumW[cur][1][t2];
    }
    // advance to next tile
    if (tc + 1 < 64) {
      ++tc;
    } else {
      ++tr;
      tc = tr;
    }
  }

  // block distance sum -> dpart[block] (plain store, no atomics)
  dacc = wave_sum64(dacc);
  if (lane == 0) partd[wave] = dacc;
  __syncthreads();
  if (threadIdx.x == 0) {
    float sacc = 0.f;
#pragma unroll
    for (int w2 = 0; w2 < 8; ++w2) sacc += partd[w2];
    dpart[blockIdx.x] = sacc;
  }
}

// ---------------- kernel C: reduce + final scalars -------------------------
// 64 blocks x 128 threads: block a reduces tot_e for rows a*128..+127 from
// part[a][t][c] (coalesced 512B rows), computes log terms inline, plus an
// 8-entry strip of dpart. Last-done block (fence + device atomic counter)
// finalizes the 4 outputs.
__global__ __launch_bounds__(128) void fin_kernel(
    const float* __restrict__ part, const float* __restrict__ dpart,
    const float* __restrict__ pos_e, const float* __restrict__ pos_d,
    float* accs, unsigned* cnt, float* __restrict__ out) {
  int a = blockIdx.x, c = threadIdx.x;
  const float* pa = part + (size_t)a * NTILE * 128 + c;
  float tot = 0.f;
#pragma unroll
  for (int t = 0; t < 64; ++t) tot += pa[(size_t)t * 128];
  int i = a * 128 + c;
  float p = pos_e[i];
  float denom = __fmaf_rn(0.5f, tot - p, p);  // p + 0.5*(tot - p)
  float lsum = LOG2F(denom) - LOG2F(p);       // -log(p/(p+neg)) / ln2
  float pdsum = pos_d[i];
  float ds = (c < 8) ? dpart[a * 8 + c] : 0.f;

  __shared__ float s1[128], s2[128], s3[128];
  s1[c] = lsum;
  s2[c] = pdsum;
  s3[c] = ds;
  __syncthreads();
  for (int w = 64; w; w >>= 1) {
    if (c < w) {
      s1[c] += s1[c + w];
      s2[c] += s2[c + w];
      s3[c] += s3[c + w];
    }
    __syncthreads();
  }
  if (c == 0) {
    atomicAdd(&accs[0], s1[0]);
    atomicAdd(&accs[1], s2[0]);
    atomicAdd(&accs[2], s3[0]);
    __threadfence();
    unsigned old = atomicAdd(cnt, 1u);
    if (old == 63u) {  // all 64 blocks' adds are visible
      float L = atomicAdd(&accs[0], 0.f);
      float PD = atomicAdd(&accs[1], 0.f);
      float DS = atomicAdd(&accs[2], 0.f);
      out[0] = L * LN2 / (float)NN;               // loss
      out[1] = 1.0f;                              // prec
      out[2] = PD / (float)(NN * 7);              // pos_d
      out[3] = (DS - PD) / ((float)NN * 8184.f);  // neg_d
    }
  }
}

extern "C" void kernel_launch(void* const* d_in, const int* in_sizes, int n_in,
                              void* d_out, int out_size, void* d_ws,
                              size_t ws_size, hipStream_t stream) {
  const float* x = (const float*)d_in[0];
  float* out = (float*)d_out;
  char* ws = (char*)d_ws;

  unsigned short* xbf = (unsigned short*)ws;          // 2 MB (swizzled layout)
  float* pos_e = (float*)(ws + (size_t)NN * DD * 2);  // 32 KB each
  float* pos_d = pos_e + NN;
  float* part = pos_d + NN;                           // 64*64*128 f32 = 2 MB
  float* dpart = part + (size_t)NTILE * NTILE * 128;  // NBLK floats
  float* accs = dpart + NBLK;                         // 3 floats
  unsigned* cnt = (unsigned*)(accs + 3);              // 1 u32

  prep_pos_kernel<<<NN / 8, 512, 0, stream>>>(x, xbf, pos_e, pos_d, accs, cnt);
  tile_kernel<<<NBLK, 512, 0, stream>>>(xbf, part, dpart);
  fin_kernel<<<64, 128, 0, stream>>>(part, dpart, pos_e, pos_d, accs, cnt,
                                     out);
}

// Round 12
// 97.088 us; speedup vs baseline: 1.2618x; 1.1536x over previous
//
#include <hip/hip_runtime.h>

#define NN 8192
#define DD 128
// ALPHA * log2(e)
#define C2 72.13475204444817f
#define LN2 0.6931471805599453f
#define NTILE 64   // 8192 / 128 row/col tiles
#define NTRI 2080  // NTILE*(NTILE+1)/2 upper-triangle tiles
#define NBLK 1024  // tile_kernel grid: 256-thr blocks, ~2 tiles each

typedef __attribute__((ext_vector_type(8))) __bf16 bf16x8;
typedef __attribute__((ext_vector_type(4))) float f32x4;

#if __has_builtin(__builtin_amdgcn_exp2f)
#define EXP2F(x) __builtin_amdgcn_exp2f(x)
#else
#define EXP2F(x) exp2f(x)
#endif
#if __has_builtin(__builtin_amdgcn_sqrtf)
#define SQRTF(x) __builtin_amdgcn_sqrtf(x)
#else
#define SQRTF(x) sqrtf(x)
#endif
#if __has_builtin(__builtin_amdgcn_logf)
#define LOG2F(x) __builtin_amdgcn_logf(x)
#else
#define LOG2F(x) log2f(x)
#endif

__device__ __forceinline__ unsigned short f2bf(float f) {
  unsigned u = __float_as_uint(f);
  u += 0x7FFFu + ((u >> 16) & 1u);  // RNE
  return (unsigned short)(u >> 16);
}

// async global->LDS, 16B per lane, LDS dest = wave-uniform base + lane*16
__device__ __forceinline__ void gload_lds16(const void* g, void* l) {
  __builtin_amdgcn_global_load_lds(
      (const __attribute__((address_space(1))) void*)g,
      (__attribute__((address_space(3))) void*)l, 16, 0, 0);
}

// ---- DPP rotate-reduction: sum over each 16-lane DPP row, result in ALL
// lanes. v_add + row_ror:{1,2,4,8} -- pure VALU, no LDS-unit traffic.
__device__ __forceinline__ float dpp_row_sum16(float v) {
  v += __int_as_float(__builtin_amdgcn_update_dpp(
      0, __float_as_int(v), 0x121, 0xf, 0xf, true));  // row_ror:1
  v += __int_as_float(__builtin_amdgcn_update_dpp(
      0, __float_as_int(v), 0x122, 0xf, 0xf, true));  // row_ror:2
  v += __int_as_float(__builtin_amdgcn_update_dpp(
      0, __float_as_int(v), 0x124, 0xf, 0xf, true));  // row_ror:4
  v += __int_as_float(__builtin_amdgcn_update_dpp(
      0, __float_as_int(v), 0x128, 0xf, 0xf, true));  // row_ror:8
  return v;
}
// full 64-lane sum: DPP within rows, shuffles across rows
__device__ __forceinline__ float wave_sum64(float v) {
  v = dpp_row_sum16(v);
  v += __shfl_xor(v, 16, 64);
  v += __shfl_xor(v, 32, 64);
  return v;
}

// ------- kernel A: fused bf16-convert + exact fp32 positives ---------------
// block = 512 threads = 8 waves = one class (targets are arange(N)//8).
// xbf is stored XOR-SWIZZLED: element e of row i lands at 16B-chunk
// (e/8)^(i&7) within the 256B row. Block 0 zeroes the tiny scalars.
__global__ __launch_bounds__(512) void prep_pos_kernel(
    const float* __restrict__ x, unsigned short* __restrict__ xbf,
    float* __restrict__ pos_e, float* __restrict__ pos_d,
    float* __restrict__ accs, unsigned* __restrict__ cnt) {
  int w = threadIdx.x >> 6;    // wave = row within class; i&7 == w
  int lane = threadIdx.x & 63;
  int i = blockIdx.x * 8 + w;

  __shared__ float xs[8][128];
  __shared__ float sqs[8];

  const float* xr = x + (size_t)i * DD;
  float a = xr[lane], b = xr[lane + 64];
  xs[w][lane] = a;
  xs[w][lane + 64] = b;

  float s = wave_sum64(__fmaf_rn(a, a, b * b));
  if (lane == 0) sqs[w] = s;
  // swizzled bf16 store: chunk t of 8 elements -> chunk t ^ w
  unsigned short* o = xbf + (size_t)i * DD;
  int t1 = lane >> 3, e1 = lane & 7;
  o[((t1 ^ w) << 3) + e1] = f2bf(a);        // elements 0..63 (chunks 0..7)
  o[64 + ((t1 ^ w) << 3) + e1] = f2bf(b);   // elements 64..127 (chunks 8..15)
  if (blockIdx.x == 0) {
    if (threadIdx.x == 0) {
      accs[0] = 0.f;
      accs[1] = 0.f;
      accs[2] = 0.f;
    }
    if (threadIdx.x == 1) cnt[0] = 0u;
  }

  __syncthreads();
  float sqi = sqs[w];
  float pe = 0.f, pd = 0.f;
  for (int j = 0; j < 8; ++j) {
    if (j == w) continue;  // wave-uniform
    float dot =
        wave_sum64(__fmaf_rn(a, xs[j][lane], b * xs[j][lane + 64]));
    float d2 = fmaxf(__fmaf_rn(-2.f, dot, sqi + sqs[j]), 1e-12f);
    float dist = SQRTF(d2);
    pe += EXP2F(__fmaf_rn(dist, -C2, C2));
    pd += dist;
  }
  if (lane == 0) {
    pos_e[i] = pe;
    pos_d[i] = pd;
  }
}

// ---------------- kernel B: triangular MFMA kernel v9 ----------------------
// R10/R11 both spilled: the B-read-redundancy fix needs ~180 VGPR, and
// 512-thread blocks at 2 blocks/CU cap VGPR at 128. v9 re-budgets: 256-thr
// blocks (4 waves), 1024 blocks (~2 tiles each). At 4-wave blocks,
// 2 blocks/CU needs only VGPR<=256 and LDS<=80KB (~72 used). Each wave owns
// a 64x64 quadrant: ar[4][4]=64 + acc[4][4]=64 + tote16 + temps ~= 180 VGPR
// -- fits. B ds_reads per CU per tile-pair: 2x4x16 = 128, HALF of v6's 256
// (the saturated LDS pipe identified by R7/R8/R9 deltas). Occupancy is
// 2 waves/SIMD but per-wave ILP doubles (64 indep MFMAs + 64 indep epilogue
// chains). MFMA count, staging, swizzle, parity, store scheme unchanged.
__global__ __launch_bounds__(256, 2) void tile_kernel(
    const unsigned short* __restrict__ xbf, float* __restrict__ part,
    float* __restrict__ dpart) {
  int lane = threadIdx.x & 63;
  int wave = threadIdx.x >> 6;        // 0..3
  int q = lane >> 4, c = lane & 15;
  int rw = wave >> 1, cw = wave & 1;  // 64-row half, 64-col half

  // chunk of the linear tile enumeration: [k0, k1), 2-3 tiles
  int k0 = (65 * blockIdx.x) >> 5, k1 = (65 * (blockIdx.x + 1)) >> 5;
  // decode k0 -> (tr, tc): P(tr) = tr*(129-tr)/2
  int tr = (int)((129.0f - SQRTF(16641.0f - 8.0f * (float)k0)) * 0.5f);
  while (tr > 0 && tr * (129 - tr) / 2 > k0) --tr;
  while ((tr + 1) * (128 - tr) / 2 <= k0) ++tr;
  int tc = tr + (k0 - tr * (129 - tr) / 2);

  __shared__ char panelB[65536];        // two 32KB B buffers
  __shared__ float rowsumW[2][2][128];  // [parity][cw][row]
  __shared__ float colsumW[2][2][128];  // [parity][rw][col]
  __shared__ float partd[4];

  int swz8 = (c & 7);  // ushort-chunk xor
  int goffB = wave * 8192 + lane * 16;

  bf16x8 ar[4][4];  // A fragments for this wave's 64-row strip
  int atr = tr;
  float dacc = 0.f;

  // prologue A-preload for tr0 (covered by the prologue barrier drain)
  {
    int I0p = tr * 128 + rw * 64;
#pragma unroll
    for (int rb = 0; rb < 4; ++rb) {
      const unsigned short* rp = xbf + (size_t)(I0p + rb * 16 + c) * DD;
#pragma unroll
      for (int ks = 0; ks < 4; ++ks)
        ar[rb][ks] = *(const bf16x8*)(rp + (((ks * 4 + q) ^ swz8) << 3));
    }
  }

  // prologue: stage B(k0); each wave stages a contiguous 8KB slice
  {
    const char* gB = (const char*)xbf + (size_t)tc * 32768;
    char* lB = panelB + wave * 8192;
#pragma unroll
    for (int t = 0; t < 8; ++t) gload_lds16(gB + t * 1024 + goffB, lB + t * 1024);
  }

  __syncthreads();  // drain prologue staging (+ A preload)

  for (int k = k0; k < k1; ++k) {
    int cur = (k - k0) & 1;
    int I0 = tr * 128 + rw * 64;  // wave row base (global)
    int J0 = tc * 128 + cw * 64;  // wave col base (global)
    bool diag = (tr == tc);

    // A-reload on row change, ISSUED BEFORE the B-prefetch so its consumer
    // waits a counted vmcnt (B loads may stay in flight).
    if (atr != tr) {
      atr = tr;
#pragma unroll
      for (int rb = 0; rb < 4; ++rb) {
        const unsigned short* rp = xbf + (size_t)(I0 + rb * 16 + c) * DD;
#pragma unroll
        for (int ks = 0; ks < 4; ++ks)
          ar[rb][ks] = *(const bf16x8*)(rp + (((ks * 4 + q) ^ swz8) << 3));
      }
    }

    // prefetch next B panel (next tile is (tr,tc+1) or (tr+1,tr+1))
    if (k + 1 < k1) {
      int tcn = (tc + 1 < 64) ? tc + 1 : tr + 1;
      const char* gB = (const char*)xbf + (size_t)tcn * 32768;
      char* lB = panelB + (cur ^ 1) * 32768 + wave * 8192;
#pragma unroll
      for (int t = 0; t < 8; ++t)
        gload_lds16(gB + t * 1024 + goffB, lB + t * 1024);
    }

    f32x4 acc[4][4];
#pragma unroll
    for (int rb = 0; rb < 4; ++rb)
#pragma unroll
      for (int cb = 0; cb < 4; ++cb)
        acc[rb][cb] = (f32x4){0.f, 0.f, 0.f, 0.f};

    // B fragments from LDS: 16 ds_read_b128/wave/tile; block total 64
    // (v6: 128) -- each read now feeds 4 MFMAs instead of 2
    {
      const char* pb = panelB + cur * 32768 + cw * 16384 + c * 256;
#pragma unroll
      for (int ks = 0; ks < 4; ++ks) {
        int koff = (ks * 64 + q * 16) ^ (swz8 << 4);
        bf16x8 br[4];
#pragma unroll
        for (int cb = 0; cb < 4; ++cb)
          br[cb] = *(const bf16x8*)(pb + cb * 4096 + koff);
#pragma unroll
        for (int rb = 0; rb < 4; ++rb)
#pragma unroll
          for (int cb = 0; cb < 4; ++cb)
            acc[rb][cb] = __builtin_amdgcn_mfma_f32_16x16x32_bf16(
                ar[rb][ks], br[cb], acc[rb][cb], 0, 0, 0);
      }
    }

    // epilogue: C/D mapping col = lane&15, row = q*4 + reg (m89-verified)
    // d2 = 2 - 2*dot (unit-norm rows). No fmax: only self-pairs can give
    // d2<0 -> NaN, and those lanes are overwritten by the cndmask below.
    float tote[16];
#pragma unroll
    for (int kk = 0; kk < 16; ++kk) tote[kk] = 0.f;
    float pcol[4] = {0.f, 0.f, 0.f, 0.f};
    float totd = 0.f;

    if (!diag) {  // 97% of tiles: no self-pair logic at all
#pragma unroll
      for (int rb = 0; rb < 4; ++rb) {
#pragma unroll
        for (int cb = 0; cb < 4; ++cb) {
#pragma unroll
          for (int r = 0; r < 4; ++r) {
            float d2 = __fmaf_rn(-2.f, acc[rb][cb][r], 2.0f);
            float dist = SQRTF(d2);
            float ex = EXP2F(__fmaf_rn(dist, -C2, C2));
            tote[rb * 4 + r] += ex;
            pcol[cb] += ex;
            totd += dist;
          }
        }
      }
      dacc += 2.f * totd;  // off-diag counts twice (symmetry)
    } else {  // diag tile: self-pair zeroing; pcol not needed (never stored)
#pragma unroll
      for (int rb = 0; rb < 4; ++rb) {
#pragma unroll
        for (int cb = 0; cb < 4; ++cb) {
          bool diagSub = (I0 + rb * 16) == (J0 + cb * 16);
#pragma unroll
          for (int r = 0; r < 4; ++r) {
            float d2 = __fmaf_rn(-2.f, acc[rb][cb][r], 2.0f);
            float dist = SQRTF(d2);
            float ex = EXP2F(__fmaf_rn(dist, -C2, C2));
            if (diagSub && (q * 4 + r) == c) {  // exclude self-pair
              ex = 0.f;
              dist = 0.f;
            }
            tote[rb * 4 + r] += ex;
            totd += dist;
          }
        }
      }
      dacc += totd;
    }

    // row sums: DPP rotate-reduce across the 16 column-lanes (pure VALU)
#pragma unroll
    for (int kk = 0; kk < 16; ++kk) tote[kk] = dpp_row_sum16(tote[kk]);
    if (c == 0) {
#pragma unroll
      for (int rb = 0; rb < 4; ++rb)
#pragma unroll
        for (int r = 0; r < 4; ++r)
          rowsumW[cur][cw][rw * 64 + rb * 16 + q * 4 + r] = tote[rb * 4 + r];
    }
    // column sums: reduce over the 4 q-groups (crosses DPP rows -> shfl)
    if (!diag) {
#pragma unroll
      for (int cb = 0; cb < 4; ++cb) {
        float cs = pcol[cb];
        cs += __shfl_xor(cs, 16, 64);
        cs += __shfl_xor(cs, 32, 64);
        if (q == 0) colsumW[cur][rw][cw * 64 + cb * 16 + c] = cs;
      }
    }

    __syncthreads();  // sums visible; drains vmcnt (B(k+1) covered by tile)

    // slot stores (each upper-triangle slot written exactly once, grid-wide)
    size_t rslot = ((size_t)tr * NTILE + tc) * 128;
    size_t cslot = ((size_t)tc * NTILE + tr) * 128;
    int t = threadIdx.x;
    if (t < 128) {
      part[rslot + t] = rowsumW[cur][0][t] + rowsumW[cur][1][t];
    } else if (!diag) {
      int t2 = t - 128;
      part[cslot + t2] = colsumW[cur][0][t2] + colsumW[cur][1][t2];
    }
    // advance to next tile
    if (tc + 1 < 64) {
      ++tc;
    } else {
      ++tr;
      tc = tr;
    }
  }

  // block distance sum -> dpart[block] (plain store, no atomics)
  dacc = wave_sum64(dacc);
  if (lane == 0) partd[wave] = dacc;
  __syncthreads();
  if (threadIdx.x == 0)
    dpart[blockIdx.x] = partd[0] + partd[1] + partd[2] + partd[3];
}

// ---------------- kernel C: reduce + final scalars -------------------------
// 64 blocks x 128 threads: block a reduces tot_e for rows a*128..+127 from
// part[a][t][c] (coalesced 512B rows), computes log terms inline, plus a
// 16-entry strip of dpart (NBLK=1024). Last-done block (fence + device
// atomic counter) finalizes the 4 outputs.
__global__ __launch_bounds__(128) void fin_kernel(
    const float* __restrict__ part, const float* __restrict__ dpart,
    const float* __restrict__ pos_e, const float* __restrict__ pos_d,
    float* accs, unsigned* cnt, float* __restrict__ out) {
  int a = blockIdx.x, c = threadIdx.x;
  const float* pa = part + (size_t)a * NTILE * 128 + c;
  float tot = 0.f;
#pragma unroll
  for (int t = 0; t < 64; ++t) tot += pa[(size_t)t * 128];
  int i = a * 128 + c;
  float p = pos_e[i];
  float denom = __fmaf_rn(0.5f, tot - p, p);  // p + 0.5*(tot - p)
  float lsum = LOG2F(denom) - LOG2F(p);       // -log(p/(p+neg)) / ln2
  float pdsum = pos_d[i];
  float ds = (c < 16) ? dpart[a * 16 + c] : 0.f;

  __shared__ float s1[128], s2[128], s3[128];
  s1[c] = lsum;
  s2[c] = pdsum;
  s3[c] = ds;
  __syncthreads();
  for (int w = 64; w; w >>= 1) {
    if (c < w) {
      s1[c] += s1[c + w];
      s2[c] += s2[c + w];
      s3[c] += s3[c + w];
    }
    __syncthreads();
  }
  if (c == 0) {
    atomicAdd(&accs[0], s1[0]);
    atomicAdd(&accs[1], s2[0]);
    atomicAdd(&accs[2], s3[0]);
    __threadfence();
    unsigned old = atomicAdd(cnt, 1u);
    if (old == 63u) {  // all 64 blocks' adds are visible
      float L = atomicAdd(&accs[0], 0.f);
      float PD = atomicAdd(&accs[1], 0.f);
      float DS = atomicAdd(&accs[2], 0.f);
      out[0] = L * LN2 / (float)NN;               // loss
      out[1] = 1.0f;                              // prec
      out[2] = PD / (float)(NN * 7);              // pos_d
      out[3] = (DS - PD) / ((float)NN * 8184.f);  // neg_d
    }
  }
}

extern "C" void kernel_launch(void* const* d_in, const int* in_sizes, int n_in,
                              void* d_out, int out_size, void* d_ws,
                              size_t ws_size, hipStream_t stream) {
  const float* x = (const float*)d_in[0];
  float* out = (float*)d_out;
  char* ws = (char*)d_ws;

  unsigned short* xbf = (unsigned short*)ws;          // 2 MB (swizzled layout)
  float* pos_e = (float*)(ws + (size_t)NN * DD * 2);  // 32 KB each
  float* pos_d = pos_e + NN;
  float* part = pos_d + NN;                           // 64*64*128 f32 = 2 MB
  float* dpart = part + (size_t)NTILE * NTILE * 128;  // NBLK floats
  float* accs = dpart + NBLK;                         // 3 floats
  unsigned* cnt = (unsigned*)(accs + 3);              // 1 u32

  prep_pos_kernel<<<NN / 8, 512, 0, stream>>>(x, xbf, pos_e, pos_d, accs, cnt);
  tile_kernel<<<NBLK, 256, 0, stream>>>(xbf, part, dpart);
  fin_kernel<<<64, 128, 0, stream>>>(part, dpart, pos_e, pos_d, accs, cnt,
                                     out);
}